// Round 1
// baseline (1795.905 us; speedup 1.0000x reference)
//
#include <hip/hip_runtime.h>

#define IMG_W 1024
#define SLICE 1048576   // 1024*1024, one (n,c) plane
#define INF_F __builtin_huge_valf()

__device__ __forceinline__ float wave_sum(float v) {
    #pragma unroll
    for (int o = 32; o > 0; o >>= 1) v += __shfl_down(v, o, 64);
    return v;
}

// Level 0: 32x32 grid of 32x32-px blocks, 289 candidates, MAD over 12288 elems.
// One workgroup per reference block; ref block held in registers (12 float4/thread).
__global__ __launch_bounds__(256) void hbma_l0(const float* __restrict__ ref,
                                               const float* __restrict__ tgt,
                                               int2* __restrict__ best0) {
    const int by = blockIdx.x;      // block-grid y (axis 1)
    const int bx = blockIdx.y;      // block-grid x (axis 0)
    const int t = threadIdx.x;
    const int lane = t & 63, wave = t >> 6;

    // thread t covers row t/8, cols 4*(t%8).. of every (n,c) slice
    const int row  = t >> 3;          // 0..31
    const int col4 = (t & 7) << 2;    // 0..28
    const int tho  = row * IMG_W + col4;

    __shared__ float partials[289 * 4];

    // stage reference block into registers
    float4 r[12];
    const float* rbase = ref + (bx * 32) * IMG_W + by * 32 + tho;
    #pragma unroll
    for (int i = 0; i < 12; ++i)
        r[i] = *(const float4*)(rbase + i * SLICE);

    for (int k = 0; k < 289; ++k) {
        const int dx = k / 17 - 8;
        const int dy = k % 17 - 8;
        const int tx = bx + dx;
        const int ty = by + dy;
        if ((unsigned)tx < 32u && (unsigned)ty < 32u) {   // wave-uniform branch
            const float* tbase = tgt + (tx * 32) * IMG_W + ty * 32 + tho;
            float s = 0.f;
            #pragma unroll
            for (int i = 0; i < 12; ++i) {
                const float4 tv = *(const float4*)(tbase + i * SLICE);
                s += fabsf(r[i].x - tv.x) + fabsf(r[i].y - tv.y)
                   + fabsf(r[i].z - tv.z) + fabsf(r[i].w - tv.w);
            }
            s = wave_sum(s);
            if (lane == 0) partials[k * 4 + wave] = s;
        } else {
            if (lane == 0) partials[k * 4 + wave] = INF_F;
        }
    }
    __syncthreads();

    // wave 0: combine partials, first-min argmin over k (lexicographic dx,dy)
    if (t < 64) {
        float bc = INF_F; int bk = 1 << 30;
        for (int k = t; k < 289; k += 64) {
            const float c = partials[k * 4 + 0] + partials[k * 4 + 1]
                          + partials[k * 4 + 2] + partials[k * 4 + 3];
            if (c < bc) { bc = c; bk = k; }   // increasing k -> first-min kept
        }
        #pragma unroll
        for (int o = 32; o > 0; o >>= 1) {
            const float oc = __shfl_down(bc, o, 64);
            const int   ok = __shfl_down(bk, o, 64);
            if (oc < bc || (oc == bc && ok < bk)) { bc = oc; bk = ok; }
        }
        if (t == 0) {
            int2 b;
            b.x = bx + bk / 17 - 8;
            b.y = by + bk % 17 - 8;
            best0[bx * 32 + by] = b;
        }
    }
}

// Level 1: 64x64 grid of 16x16-px blocks, centers = 2*parent best, 81 candidates.
// Fuses motion-vector write + predicted-frame gather.
__global__ __launch_bounds__(256) void hbma_l1(const float* __restrict__ ref,
                                               const float* __restrict__ tgt,
                                               const int2* __restrict__ best0,
                                               float* __restrict__ out) {
    const int by = blockIdx.x;      // 0..63
    const int bx = blockIdx.y;      // 0..63
    const int t = threadIdx.x;
    const int lane = t & 63, wave = t >> 6;

    __shared__ float partials[81 * 4];
    __shared__ int2 sbest;

    const int2 pb = best0[(bx >> 1) * 32 + (by >> 1)];
    const int cx = 2 * pb.x;
    const int cy = 2 * pb.y;

    // per-thread mapping: 3 float4s covering the 3072-elem block
    int off[3];
    float4 r[3];
    #pragma unroll
    for (int i = 0; i < 3; ++i) {
        const int e4  = t + 256 * i;
        const int nc  = e4 >> 6;          // 0..11
        const int w   = e4 & 63;
        const int yy  = w >> 2;           // 0..15
        const int xx4 = (w & 3) << 2;     // 0..12
        off[i] = nc * SLICE + yy * IMG_W + xx4;
        r[i] = *(const float4*)(ref + off[i] + (bx * 16) * IMG_W + by * 16);
    }

    for (int k = 0; k < 81; ++k) {
        const int dx = k / 9 - 4;
        const int dy = k % 9 - 4;
        const int tx = cx + dx;
        const int ty = cy + dy;
        if ((unsigned)tx < 64u && (unsigned)ty < 64u) {
            const float* tbase = tgt + (tx * 16) * IMG_W + ty * 16;
            float s = 0.f;
            #pragma unroll
            for (int i = 0; i < 3; ++i) {
                const float4 tv = *(const float4*)(tbase + off[i]);
                s += fabsf(r[i].x - tv.x) + fabsf(r[i].y - tv.y)
                   + fabsf(r[i].z - tv.z) + fabsf(r[i].w - tv.w);
            }
            s = wave_sum(s);
            if (lane == 0) partials[k * 4 + wave] = s;
        } else {
            if (lane == 0) partials[k * 4 + wave] = INF_F;
        }
    }
    __syncthreads();

    if (t < 64) {
        float bc = INF_F; int bk = 1 << 30;
        for (int k = t; k < 81; k += 64) {
            const float c = partials[k * 4 + 0] + partials[k * 4 + 1]
                          + partials[k * 4 + 2] + partials[k * 4 + 3];
            if (c < bc) { bc = c; bk = k; }
        }
        #pragma unroll
        for (int o = 32; o > 0; o >>= 1) {
            const float oc = __shfl_down(bc, o, 64);
            const int   ok = __shfl_down(bk, o, 64);
            if (oc < bc || (oc == bc && ok < bk)) { bc = oc; bk = ok; }
        }
        if (t == 0) {
            sbest.x = cx + bk / 9 - 4;
            sbest.y = cy + bk % 9 - 4;
        }
    }
    __syncthreads();

    const int2 fb = sbest;

    // motion vectors: out[0 .. 32767] as [N=4][2][64][64], same for all n
    if (t < 8) {
        const int n = t >> 1, ch = t & 1;
        const float v = (ch == 0) ? (float)(fb.x - bx) : (float)(fb.y - by);
        out[((n * 2 + ch) * 64 + bx) * 64 + by] = v;
    }

    // predicted frame: gather target block at fb into (bx,by)
    float* pred = out + 32768;
    const float* sbase = tgt + (fb.x * 16) * IMG_W + fb.y * 16;
    float* dbase = pred + (bx * 16) * IMG_W + by * 16;
    #pragma unroll
    for (int i = 0; i < 3; ++i)
        *(float4*)(dbase + off[i]) = *(const float4*)(sbase + off[i]);
}

extern "C" void kernel_launch(void* const* d_in, const int* in_sizes, int n_in,
                              void* d_out, int out_size, void* d_ws, size_t ws_size,
                              hipStream_t stream) {
    const float* ref = (const float*)d_in[0];
    const float* tgt = (const float*)d_in[1];
    float* out = (float*)d_out;
    int2* best0 = (int2*)d_ws;   // 1024 * 8 B

    hbma_l0<<<dim3(32, 32), 256, 0, stream>>>(ref, tgt, best0);
    hbma_l1<<<dim3(64, 64), 256, 0, stream>>>(ref, tgt, best0, out);
}

// Round 3
// 511.264 us; speedup vs baseline: 3.5127x; 3.5127x over previous
//
#include <hip/hip_runtime.h>

#define IMG_W 1024
#define SLICE 1048576   // 1024*1024, one (n,c) plane
#define INF_F __builtin_huge_valf()
#define WS_PART_FLOATS (12 * 1024 * 289)   // phase-1 partials [plane][bx*32+by][k]

// ---- DPP wave64 sum: canonical GCN row_shr/row_bcast chain, total lands in lane 63.
template <int CTRL>
__device__ __forceinline__ float dpp_add_step(float x) {
    int m = __builtin_amdgcn_update_dpp(0, __builtin_bit_cast(int, x), CTRL, 0xf, 0xf, true);
    return x + __builtin_bit_cast(float, m);
}
__device__ __forceinline__ float wave_sum63(float x) {
    x = dpp_add_step<0x111>(x);  // row_shr:1
    x = dpp_add_step<0x112>(x);  // row_shr:2
    x = dpp_add_step<0x114>(x);  // row_shr:4
    x = dpp_add_step<0x118>(x);  // row_shr:8
    x = dpp_add_step<0x142>(x);  // row_bcast:15
    x = dpp_add_step<0x143>(x);  // row_bcast:31
    return x;                    // lane 63 holds the wave total
}

// ============================================================================
// L0 phase 1: per-plane partial MAD costs with 4-ref register reuse.
// Grid (tx=32, byq=4, plane=12), 512 threads = 8 waves; wave w owns by=byq*8+w.
// Target row tx staged in LDS per dy-batch; refs (4 dx values) in registers.
// part[plane][bx*32+by][ (dx+8)*17 + (dy+8) ] = per-plane cost sum (valid only).
// ============================================================================
__global__ __launch_bounds__(512, 4) void hbma_l0_phase1(const float* __restrict__ ref,
                                                         const float* __restrict__ tgt,
                                                         float* __restrict__ part) {
    const int tx    = blockIdx.x;   // target block row 0..31
    const int byq   = blockIdx.y;   // by quarter 0..3
    const int plane = blockIdx.z;   // 0..11
    const int t = threadIdx.x;
    const int lane = t & 63, w = t >> 6;
    const int by0 = byq * 8;
    const int by  = by0 + w;

    __shared__ float tile[16 * 1024];   // 16 block-plane slices of the target row (64 KB)

    // lane's pixel footprint inside a 32x32 block-plane: rows prow+8i, cols pcol..pcol+3
    const int prow = lane >> 3;
    const int pcol = (lane & 7) << 2;

    const float* tgt_p = tgt + (size_t)plane * SLICE;
    const float* ref_p = ref + (size_t)plane * SLICE;

    for (int batch = 0; batch < 2; ++batch) {
        const int tyBase = (batch == 0) ? (by0 - 8) : by0;
        const int dyLo   = (batch == 0) ? -8 : 0;
        const int dyHi   = (batch == 0) ? -1 : 8;

        __syncthreads();   // previous batch fully consumed
        // cooperative stage: up to 16 valid slices, float4 per thread per step
        for (int idx = t; idx < 16 * 256; idx += 512) {
            const int j  = idx >> 8;
            const int ty = tyBase + j;
            if ((unsigned)ty < 32u) {
                const int ww = idx & 255;
                const int rr = ww >> 3;
                const int cc = (ww & 7) << 2;
                *(float4*)&tile[j * 1024 + rr * 32 + cc] =
                    *(const float4*)(tgt_p + (size_t)(tx * 32 + rr) * IMG_W + ty * 32 + cc);
            }
        }
        __syncthreads();

        for (int dxg = 0; dxg < 5; ++dxg) {
            // load up to 4 ref blocks (di = dxg*4+r, dx = di-8, bx = tx-dx)
            float4 rf[4][4];
            bool rvalid[4];
            #pragma unroll
            for (int r = 0; r < 4; ++r) {
                const int di = dxg * 4 + r;
                const int bx = tx - (di - 8);
                rvalid[r] = (di <= 16) && ((unsigned)bx < 32u);
                if (rvalid[r]) {
                    const float* rb = ref_p + (size_t)(bx * 32 + prow) * IMG_W + by * 32 + pcol;
                    #pragma unroll
                    for (int i = 0; i < 4; ++i)
                        rf[r][i] = *(const float4*)(rb + (size_t)i * 8 * IMG_W);
                }
            }
            for (int dy = dyLo; dy <= dyHi; ++dy) {
                const int ty = by + dy;
                if ((unsigned)ty >= 32u) continue;      // wave-uniform
                const int tbase = (ty - tyBase) * 1024 + prow * 32 + pcol;
                float4 tv[4];
                #pragma unroll
                for (int i = 0; i < 4; ++i)
                    tv[i] = *(const float4*)&tile[tbase + i * 256];
                #pragma unroll
                for (int r = 0; r < 4; ++r) {
                    if (!rvalid[r]) continue;           // wave-uniform
                    float4 a = {0.f, 0.f, 0.f, 0.f};
                    #pragma unroll
                    for (int i = 0; i < 4; ++i) {
                        a.x += __builtin_fabsf(rf[r][i].x - tv[i].x);
                        a.y += __builtin_fabsf(rf[r][i].y - tv[i].y);
                        a.z += __builtin_fabsf(rf[r][i].z - tv[i].z);
                        a.w += __builtin_fabsf(rf[r][i].w - tv[i].w);
                    }
                    const float s = wave_sum63((a.x + a.y) + (a.z + a.w));
                    if (lane == 63) {
                        const int di = dxg * 4 + r;
                        const int bx = tx - (di - 8);
                        part[((size_t)plane * 1024 + bx * 32 + by) * 289 + di * 17 + (dy + 8)] = s;
                    }
                }
            }
        }
    }
}

// ============================================================================
// L0 phase 2: sum 12 plane-partials, first-min argmin over k (lex (dx,dy)).
// Grid (by=32, bx=32), 64 threads (one wave).
// ============================================================================
__global__ __launch_bounds__(64) void hbma_l0_phase2(const float* __restrict__ part,
                                                     int2* __restrict__ best0) {
    const int by = blockIdx.x;
    const int bx = blockIdx.y;
    const int t = threadIdx.x;

    float bc = INF_F; int bk = 1 << 30;
    for (int k = t; k < 289; k += 64) {
        const int dx = k / 17 - 8, dy = k % 17 - 8;
        const int tx = bx + dx,    ty = by + dy;
        if ((unsigned)tx < 32u && (unsigned)ty < 32u) {
            float c = 0.f;
            #pragma unroll
            for (int p = 0; p < 12; ++p)
                c += part[((size_t)p * 1024 + bx * 32 + by) * 289 + k];
            if (c < bc) { bc = c; bk = k; }   // ascending k -> first-min kept
        }
    }
    #pragma unroll
    for (int o = 32; o > 0; o >>= 1) {
        const float oc = __shfl_down(bc, o, 64);
        const int   ok = __shfl_down(bk, o, 64);
        if (oc < bc || (oc == bc && ok < bk)) { bc = oc; bk = ok; }
    }
    if (t == 0) best0[bx * 32 + by] = make_int2(bx + bk / 17 - 8, by + bk % 17 - 8);
}

// ============================================================================
// L1: one WG per PARENT -> 4 children share the identical 81-candidate window.
// Each candidate block loaded once, compared against 4 register-resident refs.
// Fuses motion-vector write + predicted-frame gather.
// ============================================================================
__global__ __launch_bounds__(256) void hbma_l1(const float* __restrict__ ref,
                                               const float* __restrict__ tgt,
                                               const int2* __restrict__ best0,
                                               float* __restrict__ out) {
    const int pby = blockIdx.x;  // 0..31
    const int pbx = blockIdx.y;  // 0..31
    const int t = threadIdx.x;
    const int lane = t & 63, w = t >> 6;

    __shared__ float partials[4][81][4];
    __shared__ int2 sbest[4];

    const int2 pb = best0[pbx * 32 + pby];
    const int cx = 2 * pb.x, cy = 2 * pb.y;

    // thread's 12-px footprint of a 16x16x12 child block (3 float4s)
    int off[3];
    #pragma unroll
    for (int i = 0; i < 3; ++i) {
        const int e4 = t + 256 * i;
        const int nc = e4 >> 6;
        const int ww = e4 & 63;
        off[i] = nc * SLICE + (ww >> 2) * IMG_W + ((ww & 3) << 2);
    }
    int cbase[4];
    float4 rf[4][3];
    #pragma unroll
    for (int c = 0; c < 4; ++c) {
        const int bx = 2 * pbx + (c >> 1), by = 2 * pby + (c & 1);
        cbase[c] = (bx * 16) * IMG_W + by * 16;
        #pragma unroll
        for (int i = 0; i < 3; ++i)
            rf[c][i] = *(const float4*)(ref + cbase[c] + off[i]);
    }

    for (int k = 0; k < 81; ++k) {
        const int tx = cx + k / 9 - 4;
        const int ty = cy + k % 9 - 4;
        if ((unsigned)tx < 64u && (unsigned)ty < 64u) {   // wave-uniform
            const float* tb = tgt + (tx * 16) * IMG_W + ty * 16;
            float4 tv[3];
            #pragma unroll
            for (int i = 0; i < 3; ++i) tv[i] = *(const float4*)(tb + off[i]);
            #pragma unroll
            for (int c = 0; c < 4; ++c) {
                float4 a = {0.f, 0.f, 0.f, 0.f};
                #pragma unroll
                for (int i = 0; i < 3; ++i) {
                    a.x += __builtin_fabsf(rf[c][i].x - tv[i].x);
                    a.y += __builtin_fabsf(rf[c][i].y - tv[i].y);
                    a.z += __builtin_fabsf(rf[c][i].z - tv[i].z);
                    a.w += __builtin_fabsf(rf[c][i].w - tv[i].w);
                }
                const float s = wave_sum63((a.x + a.y) + (a.z + a.w));
                if (lane == 63) partials[c][k][w] = s;
            }
        } else if (lane == 63) {
            #pragma unroll
            for (int c = 0; c < 4; ++c) partials[c][k][w] = INF_F;
        }
    }
    __syncthreads();

    // wave w finds argmin for child w
    {
        const int c = w;
        float bc = INF_F; int bk = 1 << 30;
        for (int k = lane; k < 81; k += 64) {
            const float4 p4 = *(const float4*)&partials[c][k][0];
            const float cost = (p4.x + p4.y) + (p4.z + p4.w);
            if (cost < bc) { bc = cost; bk = k; }
        }
        #pragma unroll
        for (int o = 32; o > 0; o >>= 1) {
            const float oc = __shfl_down(bc, o, 64);
            const int   ok = __shfl_down(bk, o, 64);
            if (oc < bc || (oc == bc && ok < bk)) { bc = oc; bk = ok; }
        }
        if (lane == 0) sbest[c] = make_int2(cx + bk / 9 - 4, cy + bk % 9 - 4);
    }
    __syncthreads();

    // motion vectors: out[0..32767] as [N=4][2][64][64] (same for all n)
    if (t < 32) {
        const int c = t >> 3, n = (t >> 1) & 3, ch = t & 1;
        const int bx = 2 * pbx + (c >> 1), by = 2 * pby + (c & 1);
        const int2 fb = sbest[c];
        out[((n * 2 + ch) * 64 + bx) * 64 + by] = (ch == 0) ? (float)(fb.x - bx) : (float)(fb.y - by);
    }

    // predicted frame gather for all 4 children
    float* pred = out + 32768;
    #pragma unroll
    for (int c = 0; c < 4; ++c) {
        const int2 fb = sbest[c];
        const float* sb = tgt + (fb.x * 16) * IMG_W + fb.y * 16;
        float* db = pred + cbase[c];
        #pragma unroll
        for (int i = 0; i < 3; ++i)
            *(float4*)(db + off[i]) = *(const float4*)(sb + off[i]);
    }
}

extern "C" void kernel_launch(void* const* d_in, const int* in_sizes, int n_in,
                              void* d_out, int out_size, void* d_ws, size_t ws_size,
                              hipStream_t stream) {
    const float* ref = (const float*)d_in[0];
    const float* tgt = (const float*)d_in[1];
    float* out = (float*)d_out;

    float* part  = (float*)d_ws;                                    // 14.2 MB
    int2*  best0 = (int2*)((char*)d_ws + (size_t)WS_PART_FLOATS * 4); // 8 KB

    hbma_l0_phase1<<<dim3(32, 4, 12), 512, 0, stream>>>(ref, tgt, part);
    hbma_l0_phase2<<<dim3(32, 32), 64, 0, stream>>>(part, best0);
    hbma_l1<<<dim3(32, 32), 256, 0, stream>>>(ref, tgt, best0, out);
}